// Round 6
// baseline (140.340 us; speedup 1.0000x reference)
//
#include <hip/hip_runtime.h>
#include <math.h>

// AdderNet fused forward v6: u16 SAD, integer epilogues, patch-preload +
// s_load-only weight loops (no ds/SMEM lgkm mixing in hot loops).
//
// q(v) = round((v+8)*1024) u16; |q(a)-q(w)| = 1024*|a-w| (+-1). Pad = q(0).
// Integer requant (exact): L1 q=max(10752-((S+2)>>2),8192)
//                          L2 q=max(24832-((S+4)>>3),8192)
//                          L3 q=max(26112-((S+8)>>4),8192)
//
// d_ws (uint words): QW1[96]@0      [o16][kh3][{(w0,w1),(w2,0)}]
//                    QW2[2304]@96   [m8][o32][pk9]  word=(w[o][2m][pk],w[o][2m+1][pk])
//                    QW3[2304]@2400 [m2 16][o16][pk9]
//                    QW4[720]@4704  [m8][o10][pk9]
//
// Main: 4 img/block, 1024 blocks, 256 thr, 3 blocks/CU (LDS 53,376 B).
//  sA1[8160]: [plane32=(m8,img4)]*255, rows stride 17; after stage2:
//             part[3072]@0, A3[544]@3104 (stride 17), l4[160]@3712, logits@3968
//  sU[5184] : stages 0-1: X[img4][y28][stride17]; stages 2+: A2[plane64][9x9]

#if defined(__has_builtin)
#if __has_builtin(__builtin_amdgcn_sad_u16)
#define HAS_SAD 1
#endif
#endif

__device__ __forceinline__ unsigned sadu16(unsigned a, unsigned b, unsigned acc) {
#ifdef HAS_SAD
  return __builtin_amdgcn_sad_u16(a, b, acc);
#else
  int al = (int)(a & 0xFFFFu), ah = (int)(a >> 16);
  int bl = (int)(b & 0xFFFFu), bh = (int)(b >> 16);
  return acc + (unsigned)(al > bl ? al - bl : bl - al)
             + (unsigned)(ah > bh ? ah - bh : bh - ah);
#endif
}

__device__ __forceinline__ unsigned quant(float v) {
  return (unsigned)fmaf(v, 1024.0f, 8192.5f);  // v >= -8 by construction
}

__device__ __forceinline__ int imax(int a, int b) { return a > b ? a : b; }

#define QPAD 0x20002000u

// ---------------- weight prep: quantize + repack into d_ws ----------------
__global__ void adder_prep(const float* __restrict__ w1, const float* __restrict__ w2,
                           const float* __restrict__ w3, const float* __restrict__ w4,
                           unsigned* __restrict__ qw) {
  int k = blockIdx.x * 256 + threadIdx.x;
  if (k < 96) {
    int o = k / 6, r = k % 6, kh = r >> 1, h = r & 1;
    const float* p = w1 + o * 9 + kh * 3;
    qw[k] = h ? quant(p[2]) : (quant(p[0]) | (quant(p[1]) << 16));
  } else if (k < 2400) {
    int k2 = k - 96, m = k2 / 288, r = k2 % 288, o = r / 9, pk = r % 9;
    int s = o * 144 + 2 * m * 9 + pk;
    qw[k] = quant(w2[s]) | (quant(w2[s + 9]) << 16);
  } else if (k < 4704) {
    int k3 = k - 2400, m2 = k3 / 144, r = k3 % 144, o = r / 9, pk = r % 9;
    int s = o * 288 + 2 * m2 * 9 + pk;
    qw[k] = quant(w3[s]) | (quant(w3[s + 9]) << 16);
  } else if (k < 5424) {
    int k4 = k - 4704, m = k4 / 90, r = k4 % 90, o = r / 9, pk = r % 9;
    int s = o * 144 + 2 * m * 9 + pk;
    qw[k] = quant(w4[s]) | (quant(w4[s + 9]) << 16);
  }
}

__global__ __launch_bounds__(256, 3) void adder_main(
    const float* __restrict__ gx,
    const unsigned* __restrict__ qw,
    float* __restrict__ gout)
{
  __shared__ __align__(16) unsigned sA1[8160];
  __shared__ __align__(16) unsigned sU[5184];

  const int t = threadIdx.x;
  const int b = blockIdx.x;

  // ---------------- stage 0: stage input image, init A1 borders ----------------
  for (int k = t; k < 1568; k += 256) {
    int img = k / 392, r = k % 392, y = r / 14, xw = r % 14;
    const float2 v = *(const float2*)(gx + (size_t)(4 * b + img) * 784 + y * 28 + 2 * xw);
    sU[img * 476 + y * 17 + xw] = quant(v.x - 0.5f) | (quant(v.y - 0.5f) << 16);
  }
  for (int k = t; k < 1792; k += 256) {
    int plane = k / 56, c = k % 56;
    int y, x;
    if (c < 15)      { y = 0;      x = c; }
    else if (c < 30) { y = 14;     x = c - 15; }
    else if (c < 43) { y = c - 29; x = 0; }
    else             { y = c - 42; x = 14; }
    sA1[plane * 255 + y * 17 + x] = QPAD;
  }
  __syncthreads();

  // ---------------- stage 1: L1 [16,13,13] ----------------
  if (t < 208) {
    const int i = t >> 4, img = (t >> 2) & 3, jq = t & 3;  // j = 4jq+jj
    unsigned r[3][5], mw[3][4];
#pragma unroll
    for (int kh = 0; kh < 3; ++kh) {
      const unsigned* rp = sU + img * 476 + (2 * i + kh) * 17 + 4 * jq;
#pragma unroll
      for (int c = 0; c < 5; ++c) r[kh][c] = rp[c];
#pragma unroll
      for (int c = 0; c < 4; ++c) mw[kh][c] = r[kh][c + 1] & 0xFFFFu;
    }
#pragma unroll 1
    for (int op = 0; op < 8; ++op) {
      const unsigned* w = qw + op * 12;     // uniform -> s_load
      unsigned a0[4], a1[4];
#pragma unroll
      for (int jj = 0; jj < 4; ++jj) { a0[jj] = 0u; a1[jj] = 0u; }
#pragma unroll
      for (int kh = 0; kh < 3; ++kh) {
        unsigned wa01 = w[kh * 2], wa2 = w[kh * 2 + 1];
        unsigned wb01 = w[6 + kh * 2], wb2 = w[6 + kh * 2 + 1];
#pragma unroll
        for (int jj = 0; jj < 4; ++jj) {
          a0[jj] = sadu16(r[kh][jj], wa01, a0[jj]);
          a0[jj] = sadu16(mw[kh][jj], wa2, a0[jj]);
          a1[jj] = sadu16(r[kh][jj], wb01, a1[jj]);
          a1[jj] = sadu16(mw[kh][jj], wb2, a1[jj]);
        }
      }
      unsigned* dst = sA1 + (op * 4 + img) * 255 + (i + 1) * 17 + 4 * jq + 1;
#pragma unroll
      for (int jj = 0; jj < 4; ++jj) {
        if (4 * jq + jj < 13) {
          int q0 = imax(10752 - (int)((a0[jj] + 2u) >> 2), 8192);
          int q1 = imax(10752 - (int)((a1[jj] + 2u) >> 2), 8192);
          dst[jj] = (unsigned)q0 | ((unsigned)q1 << 16);
        }
      }
    }
  }
  __syncthreads();

  // ---------------- stage 2: L2 [32,7,7]: patch preload, s_load-only loop ----
  if (t < 196) {
    const int img = t / 49, pos = t % 49, i = pos / 7, j = pos % 7;
    // phase 1: preload all 8 plane-patches into VGPRs (LDS only)
    unsigned p[8][3][3];
#pragma unroll
    for (int m = 0; m < 8; ++m) {
      const unsigned* plane = sA1 + (m * 4 + img) * 255 + 2 * j;
#pragma unroll
      for (int kh = 0; kh < 3; ++kh) {
        const unsigned* rp = plane + (2 * i + kh) * 17;
#pragma unroll
        for (int c = 0; c < 3; ++c) p[m][kh][c] = rp[c];
      }
    }
    // phase 2: weight loop -- only SMEM operands, fully unrolled
    unsigned acc[32];
#pragma unroll
    for (int o = 0; o < 32; ++o) acc[o] = 0u;
    const unsigned* qw2 = qw + 96;
#pragma unroll
    for (int m = 0; m < 8; ++m) {
      const unsigned* wm = qw2 + m * 288;
#pragma unroll
      for (int o = 0; o < 32; ++o) {
        const unsigned* w9 = wm + o * 9;
        unsigned a = acc[o];
#pragma unroll
        for (int kh = 0; kh < 3; ++kh)
#pragma unroll
          for (int c = 0; c < 3; ++c)
            a = sadu16(p[m][kh][c], w9[kh * 3 + c], a);
        acc[o] = a;
      }
    }
#pragma unroll
    for (int m2 = 0; m2 < 16; ++m2) {
      int q0 = imax(24832 - (int)((acc[2 * m2] + 4u) >> 3), 8192);
      int q1 = imax(24832 - (int)((acc[2 * m2 + 1] + 4u) >> 3), 8192);
      sU[(m2 * 4 + img) * 81 + (i + 1) * 9 + (j + 1)] = (unsigned)q0 | ((unsigned)q1 << 16);
    }
  } else {
    // A2 border cells <- q(0) by the idle threads (sX region is dead)
    for (int k = t - 196; k < 2048; k += 60) {
      int plane = k >> 5, c = k & 31;
      int y, x;
      if (c < 9)       { y = 0; x = c; }
      else if (c < 18) { y = 8; x = c - 9; }
      else if (c < 25) { y = c - 17; x = 0; }
      else             { y = c - 24; x = 8; }
      sU[plane * 81 + y * 9 + x] = QPAD;
    }
  }
  __syncthreads();

  // ---------------- stage 3: L3 [16,4,4]: 256 thr, patch preload ----------------
  {
    const int pos = t & 15, img = (t >> 4) & 3, og = (t >> 6) & 1, mg = t >> 7;
    const int i = pos >> 2, j = pos & 3;
    unsigned p[8][3][3];
#pragma unroll
    for (int mm = 0; mm < 8; ++mm) {
      const unsigned* plane = sU + ((mg * 8 + mm) * 4 + img) * 81 + 2 * j;
#pragma unroll
      for (int kh = 0; kh < 3; ++kh) {
        const unsigned* rp = plane + (2 * i + kh) * 9;
#pragma unroll
        for (int c = 0; c < 3; ++c) p[mm][kh][c] = rp[c];
      }
    }
    unsigned acc[8];
#pragma unroll
    for (int o = 0; o < 8; ++o) acc[o] = 0u;
    const unsigned* qw3 = qw + 2400;
#pragma unroll
    for (int mm = 0; mm < 8; ++mm) {
      const unsigned* ws = qw3 + (mg * 8 + mm) * 144 + og * 72;
#pragma unroll
      for (int oo = 0; oo < 8; ++oo) {
        const unsigned* w9 = ws + oo * 9;
        unsigned a = acc[oo];
#pragma unroll
        for (int kh = 0; kh < 3; ++kh)
#pragma unroll
          for (int c = 0; c < 3; ++c)
            a = sadu16(p[mm][kh][c], w9[kh * 3 + c], a);
        acc[oo] = a;
      }
    }
    unsigned* pp = sA1 + t * 12;
    *(uint4*)(pp)     = make_uint4(acc[0], acc[1], acc[2], acc[3]);
    *(uint4*)(pp + 4) = make_uint4(acc[4], acc[5], acc[6], acc[7]);
  }
  __syncthreads();

  // reduce mg-groups -> A3 pair words @ sA1[3104..], plane stride 17
  if (t < 64) {
    const int img = t >> 4, pos = t & 15;
#pragma unroll
    for (int m = 0; m < 8; ++m) {
      const int og = m >> 2, oo = 2 * (m & 3);
      const int b0 = ((og << 6) | (img << 4) | pos) * 12;
      unsigned s0 = sA1[b0 + oo]     + sA1[b0 + 1536 + oo];
      unsigned s1 = sA1[b0 + oo + 1] + sA1[b0 + 1536 + oo + 1];
      int q0 = imax(26112 - (int)((s0 + 8u) >> 4), 8192);
      int q1 = imax(26112 - (int)((s1 + 8u) >> 4), 8192);
      sA1[3104 + (img * 8 + m) * 17 + pos] = (unsigned)q0 | ((unsigned)q1 << 16);
    }
  }
  __syncthreads();

  // ---------------- stage 4: L4 + log_softmax ----------------
  if (t < 160) {
    const int img = t / 40, r = t % 40, o = r / 4, mq = r % 4;
    const unsigned* qw4 = qw + 4704;
    unsigned acc = 0u;
#pragma unroll
    for (int mm = 0; mm < 2; ++mm) {
      const int m = mq * 2 + mm;
      const unsigned* a3 = sA1 + 3104 + (img * 8 + m) * 17;
      const unsigned* w9 = qw4 + (m * 10 + o) * 9;
#pragma unroll
      for (int kh = 0; kh < 3; ++kh)
#pragma unroll
        for (int kw = 0; kw < 3; ++kw)
          acc = sadu16(a3[kh * 4 + kw], w9[kh * 3 + kw], acc);
    }
    sA1[3712 + t] = acc;
  }
  __syncthreads();
  if (t < 40) {
    const int img = t / 10, o = t % 10;
    const unsigned* P = sA1 + 3712 + img * 40 + o * 4;
    unsigned s = P[0] + P[1] + P[2] + P[3];
    ((float*)sA1)[3968 + t] = -(float)s * (1.0f / 1024.0f);
  }
  __syncthreads();
  if (t < 40) {
    const int img = t / 10, o = t % 10;
    const float* lg = (const float*)sA1 + 3968 + img * 10;
    float mx = lg[0];
#pragma unroll
    for (int k = 1; k < 10; ++k) mx = fmaxf(mx, lg[k]);
    float sum = 0.0f;
#pragma unroll
    for (int k = 0; k < 10; ++k) sum += __expf(lg[k] - mx);
    gout[(size_t)(4 * b + img) * 10 + o] = lg[o] - mx - __logf(sum);
  }
}

extern "C" void kernel_launch(void* const* d_in, const int* in_sizes, int n_in,
                              void* d_out, int out_size, void* d_ws, size_t ws_size,
                              hipStream_t stream) {
  const float* x  = (const float*)d_in[0];
  const float* w1 = (const float*)d_in[1];
  const float* w2 = (const float*)d_in[2];
  const float* w3 = (const float*)d_in[3];
  const float* w4 = (const float*)d_in[4];
  unsigned* qw = (unsigned*)d_ws;           // 5424 words = 21.7 KB
  float* out = (float*)d_out;
  adder_prep<<<22, 256, 0, stream>>>(w1, w2, w3, w4, qw);
  adder_main<<<1024, 256, 0, stream>>>(x, qw, out);
}

// Round 7
// 117.833 us; speedup vs baseline: 1.1910x; 1.1910x over previous
//
#include <hip/hip_runtime.h>
#include <math.h>

// AdderNet fused forward v7: one wave per image. 4096 blocks x 64 threads.
// All barriers intra-wave (free) -> 12+ independent waves/CU hide latency.
//
// q(v) = round((v+8)*1024) u16; |q(a)-q(w)| = 1024*|a-w| (+-1). Pad = q(0).
// Integer requant (exact, validated R6): L1 q=max(10752-((S+2)>>2),8192)
//   L2 q=max(24832-((S+4)>>3),8192)   L3 q=max(26112-((S+8)>>4),8192)
//
// d_ws (uint words): QW1[96]@0      [o16][kh3][{(w0,w1),(w2,0)}]
//                    QW2[2304]@96   [m8][o32][pk9]  word=(w[o][2m][pk],w[o][2m+1][pk])
//                    QW3[2304]@2400 [m2 16][o16][pk9]
//                    QW4[720]@4704  [m8][o10][pk9]
//
// LDS (12,384 B -> 12-13 blocks/CU):
//  sA1[1800]: A1 8 ch-pair planes x (15 rows x 15), ghost border = q(0)
//             after stage 2: part[768]@0, A3[136]@800 (stride 17),
//             l4[40]@940, logits(float)[10]@980
//  sA2[1296]: A2 16 ch-pair planes x (9x9), ghost border = q(0)

#if defined(__has_builtin)
#if __has_builtin(__builtin_amdgcn_sad_u16)
#define HAS_SAD 1
#endif
#endif

__device__ __forceinline__ unsigned sadu16(unsigned a, unsigned b, unsigned acc) {
#ifdef HAS_SAD
  return __builtin_amdgcn_sad_u16(a, b, acc);
#else
  int al = (int)(a & 0xFFFFu), ah = (int)(a >> 16);
  int bl = (int)(b & 0xFFFFu), bh = (int)(b >> 16);
  return acc + (unsigned)(al > bl ? al - bl : bl - al)
             + (unsigned)(ah > bh ? ah - bh : bh - ah);
#endif
}

__device__ __forceinline__ unsigned quant(float v) {
  return (unsigned)fmaf(v, 1024.0f, 8192.5f);  // v >= -8 by construction
}
__device__ __forceinline__ unsigned quantx(float v) {  // quant(v - 0.5)
  return (unsigned)fmaf(v, 1024.0f, 7680.5f);
}
__device__ __forceinline__ int imax(int a, int b) { return a > b ? a : b; }

#define QPAD 0x20002000u

// ---------------- weight prep: quantize + repack into d_ws ----------------
__global__ void adder_prep(const float* __restrict__ w1, const float* __restrict__ w2,
                           const float* __restrict__ w3, const float* __restrict__ w4,
                           unsigned* __restrict__ qw) {
  int k = blockIdx.x * 256 + threadIdx.x;
  if (k < 96) {
    int o = k / 6, r = k % 6, kh = r >> 1, h = r & 1;
    const float* p = w1 + o * 9 + kh * 3;
    qw[k] = h ? quant(p[2]) : (quant(p[0]) | (quant(p[1]) << 16));
  } else if (k < 2400) {
    int k2 = k - 96, m = k2 / 288, r = k2 % 288, o = r / 9, pk = r % 9;
    int s = o * 144 + 2 * m * 9 + pk;
    qw[k] = quant(w2[s]) | (quant(w2[s + 9]) << 16);
  } else if (k < 4704) {
    int k3 = k - 2400, m2 = k3 / 144, r = k3 % 144, o = r / 9, pk = r % 9;
    int s = o * 288 + 2 * m2 * 9 + pk;
    qw[k] = quant(w3[s]) | (quant(w3[s + 9]) << 16);
  } else if (k < 5424) {
    int k4 = k - 4704, m = k4 / 90, r = k4 % 90, o = r / 9, pk = r % 9;
    int s = o * 144 + 2 * m * 9 + pk;
    qw[k] = quant(w4[s]) | (quant(w4[s + 9]) << 16);
  }
}

__global__ __launch_bounds__(64, 3) void adder_main(
    const float* __restrict__ gx,
    const unsigned* __restrict__ qw,
    float* __restrict__ gout)
{
  __shared__ __align__(16) unsigned sA1[1800];
  __shared__ __align__(16) unsigned sA2[1296];

  const int t = threadIdx.x;
  const int b = blockIdx.x;
  const float* img = gx + (size_t)b * 784;

  // ---------------- stage 0: ghost borders (A1 and A2) ----------------
  for (int k = t; k < 448; k += 64) {       // A1: 8 planes x 56 perimeter cells
    int plane = k / 56, c = k % 56;
    int y, x;
    if (c < 15)      { y = 0;      x = c; }
    else if (c < 30) { y = 14;     x = c - 15; }
    else if (c < 43) { y = c - 29; x = 0; }
    else             { y = c - 42; x = 14; }
    sA1[plane * 225 + y * 15 + x] = QPAD;
  }
  for (int k = t; k < 512; k += 64) {       // A2: 16 planes x 32 perimeter cells
    int plane = k >> 5, c = k & 31;
    int y, x;
    if (c < 9)       { y = 0; x = c; }
    else if (c < 18) { y = 8; x = c - 9; }
    else if (c < 25) { y = c - 17; x = 0; }
    else             { y = c - 24; x = 8; }
    sA2[plane * 81 + y * 9 + x] = QPAD;
  }

  // ---------------- stage 1: L1 [16,13,13], X straight from global ----------
  if (t < 52) {
    const int i = t >> 2, jq = t & 3;       // output rows i, cols j=4jq+jj
    unsigned r[3][5], mw[3][4];
#pragma unroll
    for (int kh = 0; kh < 3; ++kh) {
      const float* rp = img + (2 * i + kh) * 28 + 8 * jq;
      float4 A = *(const float4*)(rp);
      float4 B = *(const float4*)(rp + 4);
      float2 C = *(const float2*)(rp + 8);
      r[kh][0] = quantx(A.x) | (quantx(A.y) << 16);
      r[kh][1] = quantx(A.z) | (quantx(A.w) << 16);
      r[kh][2] = quantx(B.x) | (quantx(B.y) << 16);
      r[kh][3] = quantx(B.z) | (quantx(B.w) << 16);
      r[kh][4] = quantx(C.x) | (quantx(C.y) << 16);
#pragma unroll
      for (int c = 0; c < 4; ++c) mw[kh][c] = r[kh][c + 1] & 0xFFFFu;
    }
#pragma unroll 1
    for (int op = 0; op < 8; ++op) {        // output-channel pairs
      const unsigned* w = qw + op * 12;     // uniform -> s_load
      unsigned a0[4], a1[4];
#pragma unroll
      for (int jj = 0; jj < 4; ++jj) { a0[jj] = 0u; a1[jj] = 0u; }
#pragma unroll
      for (int kh = 0; kh < 3; ++kh) {
        unsigned wa01 = w[kh * 2], wa2 = w[kh * 2 + 1];
        unsigned wb01 = w[6 + kh * 2], wb2 = w[6 + kh * 2 + 1];
#pragma unroll
        for (int jj = 0; jj < 4; ++jj) {
          a0[jj] = sadu16(r[kh][jj], wa01, a0[jj]);
          a0[jj] = sadu16(mw[kh][jj], wa2, a0[jj]);
          a1[jj] = sadu16(r[kh][jj], wb01, a1[jj]);
          a1[jj] = sadu16(mw[kh][jj], wb2, a1[jj]);
        }
      }
      unsigned* dst = sA1 + op * 225 + (i + 1) * 15 + 4 * jq + 1;
#pragma unroll
      for (int jj = 0; jj < 4; ++jj) {
        if (4 * jq + jj < 13) {
          int q0 = imax(10752 - (int)((a0[jj] + 2u) >> 2), 8192);
          int q1 = imax(10752 - (int)((a1[jj] + 2u) >> 2), 8192);
          dst[jj] = (unsigned)q0 | ((unsigned)q1 << 16);
        }
      }
    }
  }
  __syncthreads();

  // ---------------- stage 2: L2 [32,7,7], all 32 o per lane ----------------
  if (t < 49) {
    const int i = t / 7, j = t % 7;
    unsigned acc[32];
#pragma unroll
    for (int o = 0; o < 32; ++o) acc[o] = 0u;
    const unsigned* qw2 = qw + 96;
#pragma unroll 1
    for (int m = 0; m < 8; ++m) {
      const unsigned* plane = sA1 + m * 225 + 2 * j;
      unsigned p[3][3];
#pragma unroll
      for (int kh = 0; kh < 3; ++kh)
#pragma unroll
        for (int c = 0; c < 3; ++c)
          p[kh][c] = plane[(2 * i + kh) * 15 + c];
      const unsigned* wm = qw2 + m * 288;   // uniform -> s_load
#pragma unroll
      for (int o = 0; o < 32; ++o) {
        const unsigned* w9 = wm + o * 9;
        unsigned a = acc[o];
#pragma unroll
        for (int kh = 0; kh < 3; ++kh)
#pragma unroll
          for (int c = 0; c < 3; ++c)
            a = sadu16(p[kh][c], w9[kh * 3 + c], a);
        acc[o] = a;
      }
    }
#pragma unroll
    for (int m2 = 0; m2 < 16; ++m2) {
      int q0 = imax(24832 - (int)((acc[2 * m2] + 4u) >> 3), 8192);
      int q1 = imax(24832 - (int)((acc[2 * m2 + 1] + 4u) >> 3), 8192);
      sA2[m2 * 81 + (i + 1) * 9 + (j + 1)] = (unsigned)q0 | ((unsigned)q1 << 16);
    }
  }
  __syncthreads();

  // ---------------- stage 3: L3 [16,4,4], 64 lanes (pos16 x og2 x mg2) -------
  {
    const int pos = t & 15, og = (t >> 4) & 1, mg = t >> 5;
    const int i = pos >> 2, j = pos & 3;
    unsigned acc[8];
#pragma unroll
    for (int o = 0; o < 8; ++o) acc[o] = 0u;
    const unsigned* qw3 = qw + 2400;
#pragma unroll 1
    for (int mm = 0; mm < 8; ++mm) {
      const int m2 = mg * 8 + mm;
      const unsigned* plane = sA2 + m2 * 81 + 2 * j;
      unsigned p[3][3];
#pragma unroll
      for (int kh = 0; kh < 3; ++kh)
#pragma unroll
        for (int c = 0; c < 3; ++c)
          p[kh][c] = plane[(2 * i + kh) * 9 + c];
      const unsigned* ws = qw3 + m2 * 144 + og * 72;  // uniform -> s_load
#pragma unroll
      for (int oo = 0; oo < 8; ++oo) {
        const unsigned* w9 = ws + oo * 9;
        unsigned a = acc[oo];
#pragma unroll
        for (int kh = 0; kh < 3; ++kh)
#pragma unroll
          for (int c = 0; c < 3; ++c)
            a = sadu16(p[kh][c], w9[kh * 3 + c], a);
        acc[oo] = a;
      }
    }
    unsigned* pp = sA1 + t * 12;            // A1 dead; 48B stride, 16B aligned
    *(uint4*)(pp)     = make_uint4(acc[0], acc[1], acc[2], acc[3]);
    *(uint4*)(pp + 4) = make_uint4(acc[4], acc[5], acc[6], acc[7]);
  }
  __syncthreads();

  // reduce mg-groups -> A3 pair words [m8][pos16] @ sA1[800..], stride 17
  if (t < 16) {
    const int pos = t;
#pragma unroll
    for (int m = 0; m < 8; ++m) {
      const int og = m >> 2, oo = 2 * (m & 3);
      const int b0 = (og * 16 + pos) * 12;
      unsigned s0 = sA1[b0 + oo]     + sA1[b0 + 384 + oo];     // mg=1: +32*12
      unsigned s1 = sA1[b0 + oo + 1] + sA1[b0 + 384 + oo + 1];
      int q0 = imax(26112 - (int)((s0 + 8u) >> 4), 8192);
      int q1 = imax(26112 - (int)((s1 + 8u) >> 4), 8192);
      sA1[800 + m * 17 + pos] = (unsigned)q0 | ((unsigned)q1 << 16);
    }
  }
  __syncthreads();

  // ---------------- stage 4: L4 + log_softmax ----------------
  if (t < 40) {
    const int o = t % 10, mq = t / 10;
    const unsigned* qw4 = qw + 4704;
    unsigned acc = 0u;
#pragma unroll
    for (int mm = 0; mm < 2; ++mm) {
      const int m = mq * 2 + mm;
      const unsigned* a3 = sA1 + 800 + m * 17;
      const unsigned* w9 = qw4 + (m * 10 + o) * 9;  // per-lane -> vector loads
#pragma unroll
      for (int kh = 0; kh < 3; ++kh)
#pragma unroll
        for (int kw = 0; kw < 3; ++kw)
          acc = sadu16(a3[kh * 4 + kw], w9[kh * 3 + kw], acc);
    }
    sA1[940 + t] = acc;
  }
  __syncthreads();
  if (t < 10) {
    unsigned s = sA1[940 + t] + sA1[950 + t] + sA1[960 + t] + sA1[970 + t];
    ((float*)sA1)[980 + t] = -(float)s * (1.0f / 1024.0f);
  }
  __syncthreads();
  if (t < 10) {
    const float* lg = (const float*)sA1 + 980;
    float mx = lg[0];
#pragma unroll
    for (int k = 1; k < 10; ++k) mx = fmaxf(mx, lg[k]);
    float sum = 0.0f;
#pragma unroll
    for (int k = 0; k < 10; ++k) sum += __expf(lg[k] - mx);
    gout[(size_t)b * 10 + t] = lg[t] - mx - __logf(sum);
  }
}

extern "C" void kernel_launch(void* const* d_in, const int* in_sizes, int n_in,
                              void* d_out, int out_size, void* d_ws, size_t ws_size,
                              hipStream_t stream) {
  const float* x  = (const float*)d_in[0];
  const float* w1 = (const float*)d_in[1];
  const float* w2 = (const float*)d_in[2];
  const float* w3 = (const float*)d_in[3];
  const float* w4 = (const float*)d_in[4];
  unsigned* qw = (unsigned*)d_ws;           // 5424 words = 21.7 KB
  float* out = (float*)d_out;
  adder_prep<<<22, 256, 0, stream>>>(w1, w2, w3, w4, qw);
  adder_main<<<4096, 64, 0, stream>>>(x, qw, out);
}